// Round 2
// baseline (357.195 us; speedup 1.0000x reference)
//
#include <hip/hip_runtime.h>

// x: (B=64, NUM_UNITS=32, IN_CH=256, UNIT=128) fp32 contiguous.
// Reference reshape is a memory reinterpret:
//   u_hat[b, i, n, u] = x_flat[b*1048576 + i*4096 + n*128 + u]
// out[b,n,u] = squash_u( (1/256) * sum_i u_hat[b,i,n,u] )
//
// Two-kernel streaming scheme:
//  K1: block = (b, c) over 64 x 16 blocks; each block reads a CONTIGUOUS
//      256 KiB chunk (i in [16c,16c+16)) with perfectly coalesced float4
//      grid-stride loads, reduces over the 16 i's in registers, writes a
//      16 KiB partial (32 n x 128 u) to ws. 134 MB read + 16 MB write.
//  K2: block = (b, n), one wave each; sums the 16 partials, squashes,
//      writes output. 16 MB read + 1 MB write.

#define ADD4(a, v) do { (a).x += (v).x; (a).y += (v).y; (a).z += (v).z; (a).w += (v).w; } while (0)

__global__ __launch_bounds__(256) void caps_partial_kernel(
    const float* __restrict__ x, float* __restrict__ ws)
{
    const int blk = blockIdx.x;          // b*16 + c
    const int b   = blk >> 4;
    const int c   = blk & 15;
    const int t   = threadIdx.x;         // 256

    // float4 indexing. b-slice stride = 262144, chunk stride = 16384.
    // Within chunk, float4 offset f = ii*1024 + n*32 + col, ii in [0,16).
    // Thread t covers f = t + 256*k, k in [0,64):
    //   col = t&31, n = (t>>5) + 8*k1 (k1=k&3), ii = k>>2.
    const float4* __restrict__ p =
        reinterpret_cast<const float4*>(x) + ((size_t)b << 18) + ((size_t)c << 14) + t;

    float4 a0 = make_float4(0.f,0.f,0.f,0.f);
    float4 a1 = a0, a2 = a0, a3 = a0;

    #pragma unroll 4
    for (int k2 = 0; k2 < 16; ++k2) {
        const float4* q = p + ((size_t)k2 << 10);
        const float4 v0 = q[0];
        const float4 v1 = q[256];
        const float4 v2 = q[512];
        const float4 v3 = q[768];
        ADD4(a0, v0); ADD4(a1, v1); ADD4(a2, v2); ADD4(a3, v3);
    }

    // partial[n][u] for this (b,c): ws4[(b*16+c)*1024 + n*32 + col],
    // and n*32+col = t + 256*k1  -> fully coalesced stores.
    float4* __restrict__ w = reinterpret_cast<float4*>(ws) + ((size_t)blk << 10) + t;
    w[0]   = a0;
    w[256] = a1;
    w[512] = a2;
    w[768] = a3;
}

__global__ __launch_bounds__(64) void caps_squash_kernel(
    const float* __restrict__ ws, float* __restrict__ out)
{
    const int blk = blockIdx.x;          // b*32 + n
    const int b   = blk >> 5;
    const int n   = blk & 31;
    const int l   = threadIdx.x;         // 64 = one wave
    const int col = l & 31;              // float4 column of unit dim
    const int h   = l >> 5;              // chunk parity

    const float4* __restrict__ w =
        reinterpret_cast<const float4*>(ws) + ((size_t)b << 14) + (n << 5) + col;

    float4 s = make_float4(0.f,0.f,0.f,0.f);
    #pragma unroll
    for (int j = 0; j < 8; ++j) {
        const float4 v = w[(size_t)(h + (j << 1)) << 10];
        ADD4(s, v);
    }
    // combine the two chunk-parity halves (lane l <-> l^32)
    s.x += __shfl_xor(s.x, 32);
    s.y += __shfl_xor(s.y, 32);
    s.z += __shfl_xor(s.z, 32);
    s.w += __shfl_xor(s.w, 32);

    const float inv = 1.0f / 256.0f;
    s.x *= inv; s.y *= inv; s.z *= inv; s.w *= inv;

    float psq = s.x*s.x + s.y*s.y + s.z*s.z + s.w*s.w;
    #pragma unroll
    for (int m = 1; m <= 16; m <<= 1)
        psq += __shfl_xor(psq, m);

    const float mag   = sqrtf(psq);
    const float scale = psq / (1.0f + psq) / (mag + 1e-5f);
    s.x *= scale; s.y *= scale; s.z *= scale; s.w *= scale;

    if (l < 32) {
        float4* o = reinterpret_cast<float4*>(out) + ((size_t)blk << 5) + col;
        *o = s;
    }
}

extern "C" void kernel_launch(void* const* d_in, const int* in_sizes, int n_in,
                              void* d_out, int out_size, void* d_ws, size_t ws_size,
                              hipStream_t stream)
{
    const float* x = (const float*)d_in[0];
    float* ws  = (float*)d_ws;
    float* out = (float*)d_out;
    caps_partial_kernel<<<64 * 16, 256, 0, stream>>>(x, ws);
    caps_squash_kernel <<<64 * 32,  64, 0, stream>>>(ws, out);
}

// Round 3
// 347.316 us; speedup vs baseline: 1.0284x; 1.0284x over previous
//
#include <hip/hip_runtime.h>

// x: (B=64, NUM_UNITS=32, IN_CH=256, UNIT=128) fp32, contiguous.
// Reference reshape is a memory reinterpret:
//   u_hat[b, i, n, u] = x_flat[b*1048576 + i*4096 + n*128 + u]
// s[b,n,u] = (1/256) * sum_i u_hat[b,i,n,u];  out = squash(s) over u (128).
// Output: (B, NUM_UNITS, UNIT, 1) = 64*32*128 fp32.
//
// Single kernel, one block per (b, n): 134 MB read + 1 MB write, ~21 us HBM
// floor. Round-2 A/B showed dur_us is dominated by a ~325 us harness reset
// floor (1 GiB ws poison + 248 MB input restore); kernel contributes ~22 us.

#define BATCH     64
#define NUM_UNITS 32
#define IN_CH     256
#define UNIT      128

__global__ __launch_bounds__(256) void capsule_squash_kernel(
    const float* __restrict__ x, float* __restrict__ out)
{
    const int blk = blockIdx.x;      // 0..2047  == b*32 + n
    const int b   = blk >> 5;
    const int n   = blk & 31;
    const int t   = threadIdx.x;     // 256 threads
    const int f4  = t & 31;          // float4 column in unit dim (32 x float4 = 128 floats)
    const int sub = t >> 5;          // 8 i-subgroups

    // float4 units: batch stride = 262144; i stride = 1024; n stride = 32
    const float4* __restrict__ xb =
        reinterpret_cast<const float4*>(x)
        + (size_t)b * 262144u + (size_t)n * 32u + (size_t)f4;

    float4 acc = make_float4(0.f, 0.f, 0.f, 0.f);
    #pragma unroll
    for (int k = 0; k < 32; ++k) {
        const int i = sub + (k << 3);            // i = sub, sub+8, ..., sub+248
        const float4 v = xb[(size_t)i * 1024u];
        acc.x += v.x; acc.y += v.y; acc.z += v.z; acc.w += v.w;
    }

    __shared__ float4 lds[8][32];
    lds[sub][f4] = acc;
    __syncthreads();

    if (t < 32) {
        float4 s = lds[0][t];
        #pragma unroll
        for (int j = 1; j < 8; ++j) {
            const float4 v = lds[j][t];
            s.x += v.x; s.y += v.y; s.z += v.z; s.w += v.w;
        }
        const float inv = 1.0f / (float)IN_CH;
        s.x *= inv; s.y *= inv; s.z *= inv; s.w *= inv;

        // mag_sq over the 128-float unit vector: reduce across lanes 0..31
        float psq = s.x*s.x + s.y*s.y + s.z*s.z + s.w*s.w;
        #pragma unroll
        for (int m = 1; m <= 16; m <<= 1)
            psq += __shfl_xor(psq, m);

        const float mag   = sqrtf(psq);
        const float scale = psq / (1.0f + psq) / (mag + 1e-5f);
        s.x *= scale; s.y *= scale; s.z *= scale; s.w *= scale;

        float4* o = reinterpret_cast<float4*>(out) + (size_t)blk * 32u + t;
        *o = s;
    }
}

extern "C" void kernel_launch(void* const* d_in, const int* in_sizes, int n_in,
                              void* d_out, int out_size, void* d_ws, size_t ws_size,
                              hipStream_t stream)
{
    const float* x = (const float*)d_in[0];
    float* out = (float*)d_out;
    capsule_squash_kernel<<<BATCH * NUM_UNITS, 256, 0, stream>>>(x, out);
}